// Round 5
// baseline (285.255 us; speedup 1.0000x reference)
//
#include <hip/hip_runtime.h>
#include <hip/hip_bf16.h>

#define B_   16
#define K_   50
#define CIN  256
#define F_   76
#define A_   3
#define NCH  85
#define OC   255
#define HW   (F_*F_)
#define NBLK (B_*F_)
#define NCELL (A_*F_)            // 228
#define SLAB (F_*NCH)            // 6460 floats per (b,a,j)

// ws floats: Wt bf16[256][256]=f[0..32768) ; bias[32768..33024) ; labrec[33024..45824) ;
//            partials[45824..55552) ; W15frag bf16[4096]=f[55552..57600) ; raw5 f32 [57600..)
#define WS_BIAS_F 32768
#define WS_LAB_F  33024
#define WS_PART_F 45824
#define WS_W15_F  55552
#define WS_RAW5_F 57600
#define RAW5_FLOATS (B_*15*HW)   // 1,386,240 floats = 5.5 MB

#define NTILE 91                 // ceil(5776/64) position tiles per batch

typedef __attribute__((ext_vector_type(8))) short short8;
typedef __attribute__((ext_vector_type(4))) float f32x4;

__device__ __constant__ float AW9[9] = {1.25f, 2.0f, 4.125f, 3.75f, 7.75f, 7.375f, 14.5f, 19.5f, 46.625f};
__device__ __constant__ float AH9[9] = {1.625f, 3.75f, 2.875f, 7.625f, 5.625f, 14.875f, 11.25f, 24.75f, 40.75f};

__device__ __forceinline__ unsigned short f2bf(float f) {
    union { float f; unsigned int u; } v; v.f = f;
    unsigned int r = v.u + 0x7fffu + ((v.u >> 16) & 1u);
    return (unsigned short)(r >> 16);
}
__device__ __forceinline__ float bf2f(unsigned short b) {
    union { unsigned int u; float f; } v; v.u = ((unsigned int)b) << 16;
    return v.f;
}
__device__ __forceinline__ float sigm(float r) { return 1.0f / (1.0f + __expf(-r)); }
__device__ __forceinline__ float bce_t(float p, float tv) {
    float pc = fminf(fmaxf(p, 1e-12f), 1.0f - 1e-7f);
    return -(tv * __logf(pc) + (1.0f - tv) * __logf(1.0f - pc));
}

// ---------------- prep ----------------
// labrec: A0={tx,ty,tw,th} A1={valid, fa(-1 if not pos), fi, fj} B0={txv,tyv,logw,logh} B1={sc,cls,0,0}
// W15 row r (r<15): orig o = (r/5)*85 + r%5  (box+obj channels of the 3 anchors)
__global__ void prep_kernel(const float* __restrict__ conv_w, const float* __restrict__ conv_b,
                            const float* __restrict__ labels, float* __restrict__ ws) {
    int bid = blockIdx.x, t = threadIdx.x;
    if (bid < 256) {
        // Wt bf16 [k][o], k = bid, o = t (o=255 pad)
        float v = (t < OC) ? conv_w[t * CIN + bid] : 0.0f;
        ((unsigned short*)ws)[bid * 256 + t] = f2bf(v);
    } else if (bid == 256) {
        ws[WS_BIAS_F + t] = (t < OC) ? conv_b[t] : 0.0f;
    } else if (bid == 257) {
        for (int idx = t; idx < B_ * K_; idx += 256) {
            const float* L = labels + idx * 5;
            float cls = L[0], xc = L[1], yc = L[2], wl = L[3], hl = L[4];
            float ssum = cls + xc + yc + wl + hl;
            float validf = (ssum > 0.0f) ? 1.0f : 0.0f;
            float tx = xc * F_, ty = yc * F_, tw = wl * F_, th = hl * F_;
            int ii = (int)tx, jj = (int)ty;
            float tarea = tw * th;
            float best = -1.0f; int bn = 0;
            #pragma unroll
            for (int n = 0; n < 9; n++) {
                float inter = fminf(tw, AW9[n]) * fminf(th, AH9[n]);
                float iou = inter / (tarea + AW9[n] * AH9[n] - inter);
                if (iou > best) { best = iou; bn = n; }
            }
            int a = bn % 3;
            bool self = (validf != 0.0f) && (bn < 3);
            float* R = ws + WS_LAB_F + idx * 16;
            R[0] = tx; R[1] = ty; R[2] = tw; R[3] = th;
            R[4] = validf; R[5] = self ? (float)a : -1.0f; R[6] = (float)ii; R[7] = (float)jj;
            R[8] = tx - (float)ii; R[9] = ty - (float)jj;
            R[10] = __logf(tw / AW9[a] + 1e-16f);
            R[11] = __logf(th / AH9[a] + 1e-16f);
            R[12] = sqrtf(2.0f - tarea / (float)HW);
            R[13] = cls; R[14] = 0.0f; R[15] = 0.0f;
        }
    } else { // bid == 258 : W15 A-fragments [ks(8)][lane(64)][jj(8)]
        unsigned short* wf = (unsigned short*)(ws + WS_W15_F);
        for (int idx = t; idx < 4096; idx += 256) {
            int ks = idx >> 9, lane = (idx >> 3) & 63, jj = idx & 7;
            int row = lane & 15;
            int k = ks * 32 + (lane >> 4) * 8 + jj;
            float v = 0.0f;
            if (row < 15) v = conv_w[((row / 5) * NCH + (row % 5)) * CIN + k];
            wf[idx] = f2bf(v);
        }
    }
}

// ---------------- conv: tile-staged GEMM raw5[b][15][hw] = W15 . x, fused with the transpose ----------------
// One block per 64-position tile: stage 64ch x 64pos chunks in LDS, MFMA per chunk, accumulate K=256.
__global__ __launch_bounds__(256) void conv_kernel(const float* __restrict__ xin,
                                                   const float* __restrict__ ws,
                                                   float* __restrict__ raw5g) {
    __shared__ float tS[64][65];
    const int t = threadIdx.x;
    const int w = t >> 6, lane = t & 63;
    const int lr = lane & 15, q = lane >> 4;
    const int bt = blockIdx.x / NTILE, tile = blockIdx.x - bt * NTILE;
    const int hw0 = tile * 64;
    const int npos = (HW - hw0 < 64) ? (HW - hw0) : 64;

    const unsigned short* wf15 = (const unsigned short*)(ws + WS_W15_F);
    short8 afr[8];
    #pragma unroll
    for (int ks = 0; ks < 8; ks++)
        afr[ks] = *(const short8*)&wf15[(ks * 64 + lane) * 8];

    f32x4 acc = (f32x4){0.0f, 0.0f, 0.0f, 0.0f};
    const float* xb = xin + (size_t)bt * CIN * HW + hw0;
    const int c_l = t >> 2, g = t & 3;
    #pragma unroll 1
    for (int cc = 0; cc < 4; cc++) {
        // stage chunk: channels cc*64+c_l, positions 0..63 (coalesced float4)
        const float* src = xb + (size_t)(cc * 64 + c_l) * HW;
        #pragma unroll
        for (int k2 = 0; k2 < 4; k2++) {
            int p_l = 4 * g + 16 * k2;
            if (p_l < npos) {
                float4 v = *(const float4*)(src + p_l);
                tS[c_l][p_l] = v.x; tS[c_l][p_l + 1] = v.y;
                tS[c_l][p_l + 2] = v.z; tS[c_l][p_l + 3] = v.w;
            }
        }
        __syncthreads();
        // wave w -> positions w*16+lr ; B-frag = 8 consecutive channels down a tS column
        #pragma unroll
        for (int m = 0; m < 2; m++) {
            float xv[8];
            #pragma unroll
            for (int jj = 0; jj < 8; jj++)
                xv[jj] = tS[m * 32 + q * 8 + jj][w * 16 + lr];
            union { short8 s; __hip_bfloat162 h[4]; } u;
            #pragma unroll
            for (int p2 = 0; p2 < 4; p2++)
                u.h[p2] = __float22bfloat162_rn(make_float2(xv[2 * p2], xv[2 * p2 + 1]));
            acc = __builtin_amdgcn_mfma_f32_16x16x32_bf16(afr[cc * 2 + m], u.s, acc, 0, 0, 0);
        }
        __syncthreads();
    }
    // C layout: col=lane&15 -> position, row=q*4+r; bias folded here
    const float* biasg = ws + WS_BIAS_F;
    const int p = w * 16 + lr;
    if (hw0 + p < HW) {
        #pragma unroll
        for (int r = 0; r < 4; r++) {
            int row = q * 4 + r;
            if (row < 15) {
                int o = (row / 5) * NCH + (row % 5);
                raw5g[((size_t)bt * 15 + row) * HW + hw0 + p] = acc[r] + biasg[o];
            }
        }
    }
}

// ---------------- fused: per-(b,j) losses + dense out_m + sparse cells ----------------
// R5: true -> read precomputed raw5 from ws; false -> inline GEMM from xin (fallback)
template<bool R5>
__global__ __launch_bounds__(320) void fused_kernel(const float* __restrict__ xin,
                                                    const float* __restrict__ ws,
                                                    float* __restrict__ d_out,
                                                    float* __restrict__ part) {
    __shared__ float raw5S[15 * F_];            // 4560 B
    __shared__ float4 LAB[K_ * 4];              // 3200 B
    __shared__ int   flagS[NCELL];              // 912 B
    __shared__ float omvS[NCELL];               // 912 B
    __shared__ float xcolS[256];                // 1024 B
    __shared__ float redS[5][5];                // 100 B

    const int t = threadIdx.x;
    const int w = t >> 6, lane = t & 63;
    const int b = blockIdx.x / F_;
    const int j = blockIdx.x % F_;

    if (t < K_ * 4) LAB[t] = ((const float4*)(ws + WS_LAB_F + b * (K_ * 16)))[t];
    const float* biasg = ws + WS_BIAS_F;

    // ---------- phase 1: raw5 row into LDS ----------
    if (R5) {
        const float* r5 = ws + WS_RAW5_F + (size_t)b * 15 * HW + j * F_;
        for (int idx = t; idx < 15 * F_; idx += 320) {
            int row = idx / F_, i = idx - row * F_;
            raw5S[idx] = r5[row * HW + i];
        }
    } else {
        const int lr = lane & 15, q = lane >> 4;
        const int col0 = (w < 4) ? (w << 4) : 60;   // tile 4 overlaps tile 3, masked below
        const unsigned short* wf15 = (const unsigned short*)(ws + WS_W15_F);
        short8 afr[8];
        #pragma unroll
        for (int ks = 0; ks < 8; ks++)
            afr[ks] = *(const short8*)&wf15[(ks * 64 + lane) * 8];
        f32x4 acc = (f32x4){0.0f, 0.0f, 0.0f, 0.0f};
        const float* xbase = xin + (size_t)b * CIN * HW + j * F_ + col0 + lr;
        #pragma unroll
        for (int ks = 0; ks < 8; ks++) {
            int kb = ks * 32 + q * 8;
            float xv[8];
            #pragma unroll
            for (int jj = 0; jj < 8; jj++) xv[jj] = xbase[(size_t)(kb + jj) * HW];
            union { short8 s; __hip_bfloat162 h[4]; } u;
            #pragma unroll
            for (int p = 0; p < 4; p++)
                u.h[p] = __float22bfloat162_rn(make_float2(xv[2 * p], xv[2 * p + 1]));
            acc = __builtin_amdgcn_mfma_f32_16x16x32_bf16(afr[ks], u.s, acc, 0, 0, 0);
        }
        if (w < 4 || lr >= 4) {
            #pragma unroll
            for (int r = 0; r < 4; r++) {
                int row = q * 4 + r;
                if (row < 15) {
                    int o = (row / 5) * NCH + (row % 5);
                    raw5S[row * F_ + col0 + lr] = acc[r] + biasg[o];
                }
            }
        }
    }
    __syncthreads();

    // ---------- phase 2: per-cell losses + flags ----------
    float lxy = 0.0f, lwh = 0.0f, lobj = 0.0f, lcls = 0.0f, l2 = 0.0f;
    if (t < NCELL) {
        int a = t / F_, i = t - a * F_;
        float x   = sigm(raw5S[(a * 5 + 0) * F_ + i]);
        float y   = sigm(raw5S[(a * 5 + 1) * F_ + i]);
        float wr  = raw5S[(a * 5 + 2) * F_ + i];
        float hr  = raw5S[(a * 5 + 3) * F_ + i];
        float obj = sigm(raw5S[(a * 5 + 4) * F_ + i]);

        float px = x + (float)i, py = y + (float)j;
        float pw = __expf(wr) * AW9[a], ph = __expf(hr) * AH9[a];
        float hpw = pw * 0.5f, hph = ph * 0.5f;
        float areap = pw * ph;
        float fa_t = (float)a, fi_t = (float)i, fj_t = (float)j;

        float maxiou = 0.0f; int mk = -1;
        #pragma unroll 2
        for (int k = 0; k < K_; k++) {
            float4 A0 = LAB[4 * k + 0];
            float4 A1 = LAB[4 * k + 1];
            float tx = A0.x, ty = A0.y, tw = A0.z, th = A0.w;
            float tlx = fmaxf(px - hpw, tx - tw * 0.5f);
            float tly = fmaxf(py - hph, ty - th * 0.5f);
            float brx = fminf(px + hpw, tx + tw * 0.5f);
            float bry = fminf(py + hph, ty + th * 0.5f);
            float iw = brx - tlx, ih = bry - tly;
            float inter = (iw > 0.0f && ih > 0.0f) ? iw * ih : 0.0f;
            float iou = __fdividef(inter, areap + tw * th - inter);
            iou = (A1.x != 0.0f) ? iou : 0.0f;
            maxiou = fmaxf(maxiou, iou);
            bool match = (A1.y == fa_t) & (A1.z == fi_t) & (A1.w == fj_t);
            mk = match ? k : mk;
        }
        float objmask = (maxiou > 0.7f) ? 0.0f : 1.0f;

        if (mk >= 0) {
            float4 B0 = LAB[4 * mk + 2];
            float4 B1 = LAB[4 * mk + 3];
            float sc = B1.x, sc2 = sc * sc;
            float txv = B0.x, tyv = B0.y, twv = B0.z, thv = B0.w;
            lxy = (bce_t(x, txv) + bce_t(y, tyv)) * sc2;
            float dw = wr - twv, dh = hr - thv;
            lwh = 0.5f * sc2 * (dw * dw + dh * dh);
            float pco = fminf(fmaxf(obj, 1e-12f), 1.0f - 1e-7f);
            lobj = -__logf(pco);
            float dx = x - txv, dy = y - tyv, dob = obj - 1.0f;
            l2 = dx * dx + dy * dy + sc2 * (dw * dw + dh * dh) + dob * dob;
            flagS[t] = mk + 1;
            omvS[t]  = obj;
        } else {
            float oo = obj * objmask;
            if (objmask != 0.0f) {
                float pco = fminf(obj, 1.0f - 1e-7f);
                lobj = -__logf(1.0f - pco);
            }
            l2 = oo * oo;
            flagS[t] = 0;
            omvS[t]  = oo;
        }
    }
    __syncthreads();

    // ---------- phase 3a: dense write (aligned float4 stream, obj folded in) ----------
    // slab float base = 6 + s*6460, base%4==2 -> head 2 floats, 1614 aligned float4, tail 2 floats
    #pragma unroll
    for (int a = 0; a < A_; a++) {
        float* slab = d_out + 6 + (size_t)((b * A_ + a) * F_ + j) * SLAB;
        const float* om = &omvS[a * F_];
        if (t == 0) { slab[0] = 0.0f; slab[1] = 0.0f; }           // ch0,1 of pos0
        if (t == 1) { slab[6458] = 0.0f; slab[6459] = 0.0f; }     // ch83,84 of pos75
        float4* dst4 = (float4*)(slab + 2);
        for (int n = t; n < 1614; n += 320) {
            int f0 = 2 + 4 * n;
            int p = f0 / 85, r = f0 - 85 * p;
            float4 v = make_float4(0.0f, 0.0f, 0.0f, 0.0f);
            if (r >= 1 && r <= 4) ((float*)&v)[4 - r] = om[p];    // channel 4 slot
            dst4[n] = v;
        }
    }
    __syncthreads();

    // ---------- phase 3b: matched labels (rare): class dots + sparse overwrite ----------
    const unsigned short* Wtg = (const unsigned short*)ws;
    for (int k = 0; k < K_; k++) {
        float4 A1 = LAB[4 * k + 1];                 // block-uniform
        int fa = (int)A1.y;
        if (fa < 0) continue;
        if ((int)A1.w != j) continue;
        int fi = (int)A1.z;
        int cell = fa * F_ + fi;
        if (flagS[cell] != k + 1) continue;         // superseded by a later label

        if (t < 256) xcolS[t] = xin[((size_t)b * CIN + t) * HW + j * F_ + fi];
        __syncthreads();
        float4 B1 = LAB[4 * k + 3];
        float sc = B1.x; int cl = (int)B1.y;
        if (t < NCH) {
            float v; int chout;
            if (t < 80) {
                int o = fa * NCH + 5 + t;
                float accv = biasg[o];
                #pragma unroll 8
                for (int kk = 0; kk < 256; kk++)
                    accv += bf2f(Wtg[kk * 256 + o]) * xcolS[kk];
                float p = sigm(accv);
                float tcv = (t == cl) ? 1.0f : 0.0f;
                lcls += bce_t(p, tcv);
                float d = p - tcv;
                l2 += d * d;
                v = p; chout = 5 + t;
            } else {
                int ch = t - 80;
                float raw = raw5S[(fa * 5 + ch) * F_ + fi];
                v = (ch == 2 || ch == 3) ? raw * sc : sigm(raw);
                chout = ch;
            }
            d_out[6 + (size_t)((b * A_ + fa) * F_ + j) * SLAB + fi * NCH + chout] = v;
        }
        __syncthreads();                            // protect xcolS reuse
    }

    // ---------- reduction -> partials ----------
    #pragma unroll
    for (int off = 32; off > 0; off >>= 1) {
        lxy  += __shfl_down(lxy, off);
        lwh  += __shfl_down(lwh, off);
        lobj += __shfl_down(lobj, off);
        lcls += __shfl_down(lcls, off);
        l2   += __shfl_down(l2, off);
    }
    if (lane == 0) {
        redS[w][0] = lxy; redS[w][1] = lwh; redS[w][2] = lobj;
        redS[w][3] = lcls; redS[w][4] = l2;
    }
    __syncthreads();
    if (t == 0) {
        float* P = part + (size_t)blockIdx.x * 8;
        #pragma unroll
        for (int q2 = 0; q2 < 5; q2++)
            P[q2] = redS[0][q2] + redS[1][q2] + redS[2][q2] + redS[3][q2] + redS[4][q2];
    }
}

// ---------------- finish ----------------
__global__ void finish_kernel(const float* __restrict__ part, float* __restrict__ d_out) {
    int t = threadIdx.x;
    float s0 = 0, s1 = 0, s2 = 0, s3 = 0, s4 = 0;
    for (int bidx = t; bidx < NBLK; bidx += 256) {
        const float* P = part + (size_t)bidx * 8;
        s0 += P[0]; s1 += P[1]; s2 += P[2]; s3 += P[3]; s4 += P[4];
    }
    #pragma unroll
    for (int off = 32; off > 0; off >>= 1) {
        s0 += __shfl_down(s0, off); s1 += __shfl_down(s1, off);
        s2 += __shfl_down(s2, off); s3 += __shfl_down(s3, off);
        s4 += __shfl_down(s4, off);
    }
    __shared__ float red[4][5];
    if ((t & 63) == 0) {
        int w = t >> 6;
        red[w][0] = s0; red[w][1] = s1; red[w][2] = s2; red[w][3] = s3; red[w][4] = s4;
    }
    __syncthreads();
    if (t == 0) {
        float r0 = red[0][0] + red[1][0] + red[2][0] + red[3][0];
        float r1 = red[0][1] + red[1][1] + red[2][1] + red[3][1];
        float r2 = red[0][2] + red[1][2] + red[2][2] + red[3][2];
        float r3 = red[0][3] + red[1][3] + red[2][3] + red[3][3];
        float r4 = red[0][4] + red[1][4] + red[2][4] + red[3][4];
        d_out[0] = r0 + r1 + r2 + r3;
        d_out[1] = r0; d_out[2] = r1; d_out[3] = r2; d_out[4] = r3; d_out[5] = r4;
    }
}

extern "C" void kernel_launch(void* const* d_in, const int* in_sizes, int n_in,
                              void* d_out, int out_size, void* d_ws, size_t ws_size,
                              hipStream_t stream) {
    const float* xin    = (const float*)d_in[0];
    const float* labels = (const float*)d_in[1];
    const float* conv_w = (const float*)d_in[2];
    const float* conv_b = (const float*)d_in[3];
    float* out  = (float*)d_out;
    float* ws   = (float*)d_ws;
    float* part = ws + WS_PART_F;

    prep_kernel<<<259, 256, 0, stream>>>(conv_w, conv_b, labels, ws);
    const size_t need = ((size_t)WS_RAW5_F + (size_t)RAW5_FLOATS) * 4u;
    if (ws_size >= need) {
        conv_kernel<<<B_ * NTILE, 256, 0, stream>>>(xin, ws, ws + WS_RAW5_F);
        fused_kernel<true><<<NBLK, 320, 0, stream>>>(xin, ws, out, part);
    } else {
        fused_kernel<false><<<NBLK, 320, 0, stream>>>(xin, ws, out, part);
    }
    finish_kernel<<<1, 256, 0, stream>>>(part, out);
}

// Round 6
// 245.714 us; speedup vs baseline: 1.1609x; 1.1609x over previous
//
#include <hip/hip_runtime.h>
#include <hip/hip_bf16.h>

#define B_   16
#define K_   50
#define CIN  256
#define F_   76
#define A_   3
#define NCH  85
#define OC   255
#define HW   (F_*F_)
#define NBLK (B_*F_)
#define NCELL (A_*F_)            // 228
#define SLAB (F_*NCH)            // 6460 floats per (b,a,j)

// ws floats: Wt bf16[256][256]=f[0..32768) ; bias[32768..33024) ; labrec[33024..45824) ;
//            partials[45824..55552) ; W15frag bf16[4096]=f[55552..57600) ;
//            W15P f32[256][16]=f[57600..61696) ; B15 f[61696..61712) ; raw5 f32 [61712..)
#define WS_BIAS_F 32768
#define WS_LAB_F  33024
#define WS_PART_F 45824
#define WS_W15_F  55552
#define WS_W15P_F 57600
#define WS_B15_F  61696
#define WS_RAW5_F 61712
#define RAW5_FLOATS (B_*15*HW)   // 1,386,240 floats = 5.5 MB

#define CTILE 128
#define NT2   46                 // ceil(5776/128)

typedef __attribute__((ext_vector_type(8))) short short8;
typedef __attribute__((ext_vector_type(4))) float f32x4;

__device__ __constant__ float AW9[9] = {1.25f, 2.0f, 4.125f, 3.75f, 7.75f, 7.375f, 14.5f, 19.5f, 46.625f};
__device__ __constant__ float AH9[9] = {1.625f, 3.75f, 2.875f, 7.625f, 5.625f, 14.875f, 11.25f, 24.75f, 40.75f};

__device__ __forceinline__ unsigned short f2bf(float f) {
    union { float f; unsigned int u; } v; v.f = f;
    unsigned int r = v.u + 0x7fffu + ((v.u >> 16) & 1u);
    return (unsigned short)(r >> 16);
}
__device__ __forceinline__ float bf2f(unsigned short b) {
    union { unsigned int u; float f; } v; v.u = ((unsigned int)b) << 16;
    return v.f;
}
__device__ __forceinline__ float sigm(float r) { return 1.0f / (1.0f + __expf(-r)); }
__device__ __forceinline__ float bce_t(float p, float tv) {
    float pc = fminf(fmaxf(p, 1e-12f), 1.0f - 1e-7f);
    return -(tv * __logf(pc) + (1.0f - tv) * __logf(1.0f - pc));
}

// ---------------- prep ----------------
// labrec: A0={tx,ty,tw,th} A1={valid, fa(-1 if not pos), fi, fj} B0={txv,tyv,logw,logh} B1={sc,cls,0,0}
// W15 row r (r<15): orig o = (r/5)*85 + r%5  (box+obj channels of the 3 anchors)
__global__ void prep_kernel(const float* __restrict__ conv_w, const float* __restrict__ conv_b,
                            const float* __restrict__ labels, float* __restrict__ ws) {
    int bid = blockIdx.x, t = threadIdx.x;
    if (bid < 256) {
        // Wt bf16 [k][o], k = bid, o = t (o=255 pad)
        float v = (t < OC) ? conv_w[t * CIN + bid] : 0.0f;
        ((unsigned short*)ws)[bid * 256 + t] = f2bf(v);
    } else if (bid == 256) {
        ws[WS_BIAS_F + t] = (t < OC) ? conv_b[t] : 0.0f;
    } else if (bid == 257) {
        for (int idx = t; idx < B_ * K_; idx += 256) {
            const float* L = labels + idx * 5;
            float cls = L[0], xc = L[1], yc = L[2], wl = L[3], hl = L[4];
            float ssum = cls + xc + yc + wl + hl;
            float validf = (ssum > 0.0f) ? 1.0f : 0.0f;
            float tx = xc * F_, ty = yc * F_, tw = wl * F_, th = hl * F_;
            int ii = (int)tx, jj = (int)ty;
            float tarea = tw * th;
            float best = -1.0f; int bn = 0;
            #pragma unroll
            for (int n = 0; n < 9; n++) {
                float inter = fminf(tw, AW9[n]) * fminf(th, AH9[n]);
                float iou = inter / (tarea + AW9[n] * AH9[n] - inter);
                if (iou > best) { best = iou; bn = n; }
            }
            int a = bn % 3;
            bool self = (validf != 0.0f) && (bn < 3);
            float* R = ws + WS_LAB_F + idx * 16;
            R[0] = tx; R[1] = ty; R[2] = tw; R[3] = th;
            R[4] = validf; R[5] = self ? (float)a : -1.0f; R[6] = (float)ii; R[7] = (float)jj;
            R[8] = tx - (float)ii; R[9] = ty - (float)jj;
            R[10] = __logf(tw / AW9[a] + 1e-16f);
            R[11] = __logf(th / AH9[a] + 1e-16f);
            R[12] = sqrtf(2.0f - tarea / (float)HW);
            R[13] = cls; R[14] = 0.0f; R[15] = 0.0f;
        }
    } else if (bid == 258) { // W15 A-fragments [ks(8)][lane(64)][jj(8)] (bf16, fallback path)
        unsigned short* wf = (unsigned short*)(ws + WS_W15_F);
        for (int idx = t; idx < 4096; idx += 256) {
            int ks = idx >> 9, lane = (idx >> 3) & 63, jj = idx & 7;
            int row = lane & 15;
            int k = ks * 32 + (lane >> 4) * 8 + jj;
            float v = 0.0f;
            if (row < 15) v = conv_w[((row / 5) * NCH + (row % 5)) * CIN + k];
            wf[idx] = f2bf(v);
        }
    } else { // bid == 259 : W15 padded f32 [c][16] + bias15
        for (int idx = t; idx < 4096; idx += 256) {
            int c = idx >> 4, r = idx & 15;
            float v = 0.0f;
            if (r < 15) v = conv_w[((r / 5) * NCH + (r % 5)) * CIN + c];
            ws[WS_W15P_F + idx] = v;
        }
        if (t < 16) ws[WS_B15_F + t] = (t < 15) ? conv_b[(t / 5) * NCH + (t % 5)] : 0.0f;
    }
}

// ---------------- conv: streaming VALU GEMM raw5[b][15][hw] = W15 . x + b15 ----------------
// One thread per position; coalesced x loads; wave-uniform W reads (scalar path); no LDS.
__global__ __launch_bounds__(128) void conv_kernel(const float* __restrict__ xin,
                                                   const float* __restrict__ ws,
                                                   float* __restrict__ raw5g) {
    const int t = threadIdx.x;
    const int bt = blockIdx.x / NT2, tile = blockIdx.x - bt * NT2;
    const int p = tile * CTILE + t;
    const bool ok = p < HW;
    const float* xp = xin + (size_t)bt * CIN * HW + (ok ? p : 0);
    const float* Wp = ws + WS_W15P_F;

    float acc[15];
    #pragma unroll
    for (int r = 0; r < 15; r++) acc[r] = ws[WS_B15_F + r];

    #pragma unroll 4
    for (int c = 0; c < 256; c++) {
        float xv = xp[(size_t)c * HW];
        #pragma unroll
        for (int r = 0; r < 15; r++) acc[r] = fmaf(xv, Wp[c * 16 + r], acc[r]);
    }

    if (ok) {
        float* dst = raw5g + (size_t)bt * 15 * HW + p;
        #pragma unroll
        for (int r = 0; r < 15; r++) dst[(size_t)r * HW] = acc[r];
    }
}

// ---------------- fused: per-(b,j) losses + dense out_m + sparse cells ----------------
// R5: true -> read precomputed raw5 from ws; false -> inline GEMM from xin (fallback)
template<bool R5>
__global__ __launch_bounds__(320) void fused_kernel(const float* __restrict__ xin,
                                                    const float* __restrict__ ws,
                                                    float* __restrict__ d_out,
                                                    float* __restrict__ part) {
    __shared__ float raw5S[15 * F_];            // 4560 B
    __shared__ float4 LAB[K_ * 4];              // 3200 B
    __shared__ int   flagS[NCELL];              // 912 B
    __shared__ float omvS[NCELL];               // 912 B
    __shared__ float xcolS[256];                // 1024 B
    __shared__ float redS[5][5];                // 100 B

    const int t = threadIdx.x;
    const int w = t >> 6, lane = t & 63;
    const int b = blockIdx.x / F_;
    const int j = blockIdx.x % F_;

    if (t < K_ * 4) LAB[t] = ((const float4*)(ws + WS_LAB_F + b * (K_ * 16)))[t];
    const float* biasg = ws + WS_BIAS_F;

    // ---------- phase 1: raw5 row into LDS ----------
    if (R5) {
        const float* r5 = ws + WS_RAW5_F + (size_t)b * 15 * HW + j * F_;
        for (int idx = t; idx < 15 * F_; idx += 320) {
            int row = idx / F_, i = idx - row * F_;
            raw5S[idx] = r5[row * HW + i];
        }
    } else {
        const int lr = lane & 15, q = lane >> 4;
        const int col0 = (w < 4) ? (w << 4) : 60;   // tile 4 overlaps tile 3, masked below
        const unsigned short* wf15 = (const unsigned short*)(ws + WS_W15_F);
        short8 afr[8];
        #pragma unroll
        for (int ks = 0; ks < 8; ks++)
            afr[ks] = *(const short8*)&wf15[(ks * 64 + lane) * 8];
        f32x4 acc = (f32x4){0.0f, 0.0f, 0.0f, 0.0f};
        const float* xbase = xin + (size_t)b * CIN * HW + j * F_ + col0 + lr;
        #pragma unroll
        for (int ks = 0; ks < 8; ks++) {
            int kb = ks * 32 + q * 8;
            float xv[8];
            #pragma unroll
            for (int jj = 0; jj < 8; jj++) xv[jj] = xbase[(size_t)(kb + jj) * HW];
            union { short8 s; __hip_bfloat162 h[4]; } u;
            #pragma unroll
            for (int p = 0; p < 4; p++)
                u.h[p] = __float22bfloat162_rn(make_float2(xv[2 * p], xv[2 * p + 1]));
            acc = __builtin_amdgcn_mfma_f32_16x16x32_bf16(afr[ks], u.s, acc, 0, 0, 0);
        }
        if (w < 4 || lr >= 4) {
            #pragma unroll
            for (int r = 0; r < 4; r++) {
                int row = q * 4 + r;
                if (row < 15) {
                    int o = (row / 5) * NCH + (row % 5);
                    raw5S[row * F_ + col0 + lr] = acc[r] + biasg[o];
                }
            }
        }
    }
    __syncthreads();

    // ---------- phase 2: per-cell losses + flags ----------
    float lxy = 0.0f, lwh = 0.0f, lobj = 0.0f, lcls = 0.0f, l2 = 0.0f;
    if (t < NCELL) {
        int a = t / F_, i = t - a * F_;
        float x   = sigm(raw5S[(a * 5 + 0) * F_ + i]);
        float y   = sigm(raw5S[(a * 5 + 1) * F_ + i]);
        float wr  = raw5S[(a * 5 + 2) * F_ + i];
        float hr  = raw5S[(a * 5 + 3) * F_ + i];
        float obj = sigm(raw5S[(a * 5 + 4) * F_ + i]);

        float px = x + (float)i, py = y + (float)j;
        float pw = __expf(wr) * AW9[a], ph = __expf(hr) * AH9[a];
        float hpw = pw * 0.5f, hph = ph * 0.5f;
        float areap = pw * ph;
        float fa_t = (float)a, fi_t = (float)i, fj_t = (float)j;

        float maxiou = 0.0f; int mk = -1;
        #pragma unroll 2
        for (int k = 0; k < K_; k++) {
            float4 A0 = LAB[4 * k + 0];
            float4 A1 = LAB[4 * k + 1];
            float tx = A0.x, ty = A0.y, tw = A0.z, th = A0.w;
            float tlx = fmaxf(px - hpw, tx - tw * 0.5f);
            float tly = fmaxf(py - hph, ty - th * 0.5f);
            float brx = fminf(px + hpw, tx + tw * 0.5f);
            float bry = fminf(py + hph, ty + th * 0.5f);
            float iw = brx - tlx, ih = bry - tly;
            float inter = (iw > 0.0f && ih > 0.0f) ? iw * ih : 0.0f;
            float iou = __fdividef(inter, areap + tw * th - inter);
            iou = (A1.x != 0.0f) ? iou : 0.0f;
            maxiou = fmaxf(maxiou, iou);
            bool match = (A1.y == fa_t) & (A1.z == fi_t) & (A1.w == fj_t);
            mk = match ? k : mk;
        }
        float objmask = (maxiou > 0.7f) ? 0.0f : 1.0f;

        if (mk >= 0) {
            float4 B0 = LAB[4 * mk + 2];
            float4 B1 = LAB[4 * mk + 3];
            float sc = B1.x, sc2 = sc * sc;
            float txv = B0.x, tyv = B0.y, twv = B0.z, thv = B0.w;
            lxy = (bce_t(x, txv) + bce_t(y, tyv)) * sc2;
            float dw = wr - twv, dh = hr - thv;
            lwh = 0.5f * sc2 * (dw * dw + dh * dh);
            float pco = fminf(fmaxf(obj, 1e-12f), 1.0f - 1e-7f);
            lobj = -__logf(pco);
            float dx = x - txv, dy = y - tyv, dob = obj - 1.0f;
            l2 = dx * dx + dy * dy + sc2 * (dw * dw + dh * dh) + dob * dob;
            flagS[t] = mk + 1;
            omvS[t]  = obj;
        } else {
            float oo = obj * objmask;
            if (objmask != 0.0f) {
                float pco = fminf(obj, 1.0f - 1e-7f);
                lobj = -__logf(1.0f - pco);
            }
            l2 = oo * oo;
            flagS[t] = 0;
            omvS[t]  = oo;
        }
    }
    __syncthreads();

    // ---------- phase 3a: dense write (aligned float4 stream, obj folded in) ----------
    // slab float base = 6 + s*6460, base%4==2 -> head 2 floats, 1614 aligned float4, tail 2 floats
    #pragma unroll
    for (int a = 0; a < A_; a++) {
        float* slab = d_out + 6 + (size_t)((b * A_ + a) * F_ + j) * SLAB;
        const float* om = &omvS[a * F_];
        if (t == 0) { slab[0] = 0.0f; slab[1] = 0.0f; }           // ch0,1 of pos0
        if (t == 1) { slab[6458] = 0.0f; slab[6459] = 0.0f; }     // ch83,84 of pos75
        float4* dst4 = (float4*)(slab + 2);
        for (int n = t; n < 1614; n += 320) {
            int f0 = 2 + 4 * n;
            int p = f0 / 85, r = f0 - 85 * p;
            float4 v = make_float4(0.0f, 0.0f, 0.0f, 0.0f);
            if (r >= 1 && r <= 4) ((float*)&v)[4 - r] = om[p];    // channel 4 slot
            dst4[n] = v;
        }
    }
    __syncthreads();

    // ---------- phase 3b: matched labels (rare): class dots + sparse overwrite ----------
    const unsigned short* Wtg = (const unsigned short*)ws;
    for (int k = 0; k < K_; k++) {
        float4 A1 = LAB[4 * k + 1];                 // block-uniform
        int fa = (int)A1.y;
        if (fa < 0) continue;
        if ((int)A1.w != j) continue;
        int fi = (int)A1.z;
        int cell = fa * F_ + fi;
        if (flagS[cell] != k + 1) continue;         // superseded by a later label

        if (t < 256) xcolS[t] = xin[((size_t)b * CIN + t) * HW + j * F_ + fi];
        __syncthreads();
        float4 B1 = LAB[4 * k + 3];
        float sc = B1.x; int cl = (int)B1.y;
        if (t < NCH) {
            float v; int chout;
            if (t < 80) {
                int o = fa * NCH + 5 + t;
                float accv = biasg[o];
                #pragma unroll 8
                for (int kk = 0; kk < 256; kk++)
                    accv += bf2f(Wtg[kk * 256 + o]) * xcolS[kk];
                float p = sigm(accv);
                float tcv = (t == cl) ? 1.0f : 0.0f;
                lcls += bce_t(p, tcv);
                float d = p - tcv;
                l2 += d * d;
                v = p; chout = 5 + t;
            } else {
                int ch = t - 80;
                float raw = raw5S[(fa * 5 + ch) * F_ + fi];
                v = (ch == 2 || ch == 3) ? raw * sc : sigm(raw);
                chout = ch;
            }
            d_out[6 + (size_t)((b * A_ + fa) * F_ + j) * SLAB + fi * NCH + chout] = v;
        }
        __syncthreads();                            // protect xcolS reuse
    }

    // ---------- reduction -> partials ----------
    #pragma unroll
    for (int off = 32; off > 0; off >>= 1) {
        lxy  += __shfl_down(lxy, off);
        lwh  += __shfl_down(lwh, off);
        lobj += __shfl_down(lobj, off);
        lcls += __shfl_down(lcls, off);
        l2   += __shfl_down(l2, off);
    }
    if (lane == 0) {
        redS[w][0] = lxy; redS[w][1] = lwh; redS[w][2] = lobj;
        redS[w][3] = lcls; redS[w][4] = l2;
    }
    __syncthreads();
    if (t == 0) {
        float* P = part + (size_t)blockIdx.x * 8;
        #pragma unroll
        for (int q2 = 0; q2 < 5; q2++)
            P[q2] = redS[0][q2] + redS[1][q2] + redS[2][q2] + redS[3][q2] + redS[4][q2];
    }
}

// ---------------- finish ----------------
__global__ void finish_kernel(const float* __restrict__ part, float* __restrict__ d_out) {
    int t = threadIdx.x;
    float s0 = 0, s1 = 0, s2 = 0, s3 = 0, s4 = 0;
    for (int bidx = t; bidx < NBLK; bidx += 256) {
        const float* P = part + (size_t)bidx * 8;
        s0 += P[0]; s1 += P[1]; s2 += P[2]; s3 += P[3]; s4 += P[4];
    }
    #pragma unroll
    for (int off = 32; off > 0; off >>= 1) {
        s0 += __shfl_down(s0, off); s1 += __shfl_down(s1, off);
        s2 += __shfl_down(s2, off); s3 += __shfl_down(s3, off);
        s4 += __shfl_down(s4, off);
    }
    __shared__ float red[4][5];
    if ((t & 63) == 0) {
        int w = t >> 6;
        red[w][0] = s0; red[w][1] = s1; red[w][2] = s2; red[w][3] = s3; red[w][4] = s4;
    }
    __syncthreads();
    if (t == 0) {
        float r0 = red[0][0] + red[1][0] + red[2][0] + red[3][0];
        float r1 = red[0][1] + red[1][1] + red[2][1] + red[3][1];
        float r2 = red[0][2] + red[1][2] + red[2][2] + red[3][2];
        float r3 = red[0][3] + red[1][3] + red[2][3] + red[3][3];
        float r4 = red[0][4] + red[1][4] + red[2][4] + red[3][4];
        d_out[0] = r0 + r1 + r2 + r3;
        d_out[1] = r0; d_out[2] = r1; d_out[3] = r2; d_out[4] = r3; d_out[5] = r4;
    }
}

extern "C" void kernel_launch(void* const* d_in, const int* in_sizes, int n_in,
                              void* d_out, int out_size, void* d_ws, size_t ws_size,
                              hipStream_t stream) {
    const float* xin    = (const float*)d_in[0];
    const float* labels = (const float*)d_in[1];
    const float* conv_w = (const float*)d_in[2];
    const float* conv_b = (const float*)d_in[3];
    float* out  = (float*)d_out;
    float* ws   = (float*)d_ws;
    float* part = ws + WS_PART_F;

    prep_kernel<<<260, 256, 0, stream>>>(conv_w, conv_b, labels, ws);
    const size_t need = ((size_t)WS_RAW5_F + (size_t)RAW5_FLOATS) * 4u;
    if (ws_size >= need) {
        conv_kernel<<<B_ * NT2, CTILE, 0, stream>>>(xin, ws, ws + WS_RAW5_F);
        fused_kernel<true><<<NBLK, 320, 0, stream>>>(xin, ws, out, part);
    } else {
        fused_kernel<false><<<NBLK, 320, 0, stream>>>(xin, ws, out, part);
    }
    finish_kernel<<<1, 256, 0, stream>>>(part, out);
}

// Round 7
// 224.652 us; speedup vs baseline: 1.2698x; 1.0938x over previous
//
#include <hip/hip_runtime.h>
#include <hip/hip_bf16.h>

#define B_   16
#define K_   50
#define CIN  256
#define F_   76
#define A_   3
#define NCH  85
#define OC   255
#define HW   (F_*F_)
#define SLAB (F_*NCH)            // 6460 floats per (b,a,j)

// ws float layout
#define WS_BIAS_F 0              // 256 (conv_b padded)
#define WS_LAB_F  256            // 16*50*16 = 12800
#define WS_W15P_F 13056          // 256*16 = 4096
#define WS_B15_F  17152          // 16
#define WS_CNT_F  17168          // 1 (int)
#define WS_REC_F  17184          // 800*8 = 6400
#define WS_PART_F 23584          // 1536*8 = 12288
#define WS_OMV_F  35872          // 16*3*5776 = 277248
#define WS_END_F  313120         // 1.25 MB

#define NTL   46                 // 128-position tiles per batch (46*128 >= 5776)
#define NCONV (B_*NTL)           // 736
#define NREC  800
#define NROW  (NCONV + NREC)     // 1536

__device__ __constant__ float AW9[9] = {1.25f, 2.0f, 4.125f, 3.75f, 7.75f, 7.375f, 14.5f, 19.5f, 46.625f};
__device__ __constant__ float AH9[9] = {1.625f, 3.75f, 2.875f, 7.625f, 5.625f, 14.875f, 11.25f, 24.75f, 40.75f};

__device__ __forceinline__ float sigm(float r) { return 1.0f / (1.0f + __expf(-r)); }
__device__ __forceinline__ float bce_t(float p, float tv) {
    float pc = fminf(fmaxf(p, 1e-12f), 1.0f - 1e-7f);
    return -(tv * __logf(pc) + (1.0f - tv) * __logf(1.0f - pc));
}

// ---------------- prep ----------------
// labrec: A0={tx,ty,tw,th} A1={valid, fa(-1 if not pos), fi, fj} B0={txv,tyv,logw,logh} B1={sc,cls,0,0}
__global__ void prep_kernel(const float* __restrict__ conv_w, const float* __restrict__ conv_b,
                            const float* __restrict__ labels, float* __restrict__ ws) {
    int bid = blockIdx.x, t = threadIdx.x;
    if (bid == 0) {
        ws[WS_BIAS_F + t] = (t < OC) ? conv_b[t] : 0.0f;
    } else if (bid == 1) {
        for (int idx = t; idx < B_ * K_; idx += 256) {
            const float* L = labels + idx * 5;
            float cls = L[0], xc = L[1], yc = L[2], wl = L[3], hl = L[4];
            float ssum = cls + xc + yc + wl + hl;
            float validf = (ssum > 0.0f) ? 1.0f : 0.0f;
            float tx = xc * F_, ty = yc * F_, tw = wl * F_, th = hl * F_;
            int ii = (int)tx, jj = (int)ty;
            float tarea = tw * th;
            float best = -1.0f; int bn = 0;
            #pragma unroll
            for (int n = 0; n < 9; n++) {
                float inter = fminf(tw, AW9[n]) * fminf(th, AH9[n]);
                float iou = inter / (tarea + AW9[n] * AH9[n] - inter);
                if (iou > best) { best = iou; bn = n; }
            }
            int a = bn % 3;
            bool self = (validf != 0.0f) && (bn < 3);
            float* R = ws + WS_LAB_F + idx * 16;
            R[0] = tx; R[1] = ty; R[2] = tw; R[3] = th;
            R[4] = validf; R[5] = self ? (float)a : -1.0f; R[6] = (float)ii; R[7] = (float)jj;
            R[8] = tx - (float)ii; R[9] = ty - (float)jj;
            R[10] = __logf(tw / AW9[a] + 1e-16f);
            R[11] = __logf(th / AH9[a] + 1e-16f);
            R[12] = sqrtf(2.0f - tarea / (float)HW);
            R[13] = cls; R[14] = 0.0f; R[15] = 0.0f;
        }
    } else { // W15 padded f32 [c][16] + bias15 + counter reset
        for (int idx = t; idx < 4096; idx += 256) {
            int c = idx >> 4, r = idx & 15;
            float v = 0.0f;
            if (r < 15) v = conv_w[((r / 5) * NCH + (r % 5)) * CIN + c];
            ws[WS_W15P_F + idx] = v;
        }
        if (t < 16) ws[WS_B15_F + t] = (t < 15) ? conv_b[(t / 5) * NCH + (t % 5)] : 0.0f;
        if (t == 16) *(int*)(ws + WS_CNT_F) = 0;
    }
}

// ---------------- convloss: per-position conv (regs) + per-cell losses + omv + records ----------------
// Block = (b, tile of 128 positions); 256 threads; wave-pair channel split (scalar W reads).
__global__ __launch_bounds__(256) void convloss_kernel(const float* __restrict__ xin,
                                                       float* __restrict__ ws) {
    __shared__ float4 LAB[K_ * 4];       // 3200 B
    __shared__ float accS[128][16];      // 8192 B
    __shared__ float redS[2][4];

    const int t = threadIdx.x;
    const int blk = blockIdx.x;
    const int b = blk / NTL, tile = blk - b * NTL;
    const int ph = t & 127;
    const int p0 = tile * 128 + ph;
    const bool ok = p0 < HW;
    const int p = ok ? p0 : HW - 1;
    const int half = __builtin_amdgcn_readfirstlane(t) >> 7;   // wave-uniform: waves 0,1 -> 0; 2,3 -> 1

    if (t < K_ * 4) LAB[t] = ((const float4*)(ws + WS_LAB_F + b * (K_ * 16)))[t];

    // ---- conv: this thread's 128-channel half, software-pipelined 8-wide ----
    const float* xp = xin + (size_t)b * CIN * HW + (size_t)half * 128 * HW + p;
    const float* Wp = ws + WS_W15P_F + half * 128 * 16;

    float acc[15];
    #pragma unroll
    for (int r = 0; r < 15; r++) acc[r] = 0.0f;

    float xv[8];
    #pragma unroll
    for (int u = 0; u < 8; u++) xv[u] = xp[(size_t)u * HW];
    #pragma unroll 1
    for (int c8 = 0; c8 < 16; c8++) {
        float xn[8];
        const int cnx = (c8 < 15) ? (c8 + 1) : 15;
        #pragma unroll
        for (int u = 0; u < 8; u++) xn[u] = xp[(size_t)(cnx * 8 + u) * HW];
        #pragma unroll
        for (int u = 0; u < 8; u++) {
            const float xvu = xv[u];
            const float* wrow = Wp + (c8 * 8 + u) * 16;   // uniform -> scalar loads
            #pragma unroll
            for (int r = 0; r < 15; r++) acc[r] = fmaf(xvu, wrow[r], acc[r]);
        }
        #pragma unroll
        for (int u = 0; u < 8; u++) xv[u] = xn[u];
    }

    if (half) {
        #pragma unroll
        for (int r = 0; r < 15; r++) accS[ph][r] = acc[r];
    }
    __syncthreads();

    // ---- loss phase on threads 0..127 ----
    float lxy = 0.0f, lwh = 0.0f, lobj = 0.0f, l2 = 0.0f;
    if (t < 128 && ok) {
        #pragma unroll
        for (int r = 0; r < 15; r++) acc[r] += accS[ph][r] + ws[WS_B15_F + r];
        const int j = p / F_, i = p - j * F_;
        const float fi_t = (float)i, fj_t = (float)j;
        float X[3], Y[3], WR[3], HR[3], OB[3], HPW[3], HPH[3], ARP[3], PX[3], PY[3];
        #pragma unroll
        for (int a = 0; a < 3; a++) {
            X[a] = sigm(acc[a * 5 + 0]); Y[a] = sigm(acc[a * 5 + 1]);
            WR[a] = acc[a * 5 + 2]; HR[a] = acc[a * 5 + 3]; OB[a] = sigm(acc[a * 5 + 4]);
            PX[a] = X[a] + fi_t; PY[a] = Y[a] + fj_t;
            float pw = __expf(WR[a]) * AW9[a], phh = __expf(HR[a]) * AH9[a];
            HPW[a] = pw * 0.5f; HPH[a] = phh * 0.5f; ARP[a] = pw * phh;
        }
        float mxi[3] = {0.0f, 0.0f, 0.0f}; int mk[3] = {-1, -1, -1};
        #pragma unroll 2
        for (int k = 0; k < K_; k++) {
            float4 A0 = LAB[4 * k], A1 = LAB[4 * k + 1];
            float tx = A0.x, ty = A0.y, tw = A0.z, th = A0.w;
            float tlx0 = tx - tw * 0.5f, tly0 = ty - th * 0.5f;
            float brx0 = tx + tw * 0.5f, bry0 = ty + th * 0.5f;
            float ta = tw * th, va = A1.x;
            #pragma unroll
            for (int a = 0; a < 3; a++) {
                float tlx = fmaxf(PX[a] - HPW[a], tlx0);
                float tly = fmaxf(PY[a] - HPH[a], tly0);
                float brx = fminf(PX[a] + HPW[a], brx0);
                float bry = fminf(PY[a] + HPH[a], bry0);
                float iw = brx - tlx, ih = bry - tly;
                float inter = (iw > 0.0f && ih > 0.0f) ? iw * ih : 0.0f;
                float iou = __fdividef(inter, ARP[a] + ta - inter);
                iou = (va != 0.0f) ? iou : 0.0f;
                mxi[a] = fmaxf(mxi[a], iou);
                bool match = (A1.y == (float)a) & (A1.z == fi_t) & (A1.w == fj_t);
                mk[a] = match ? k : mk[a];
            }
        }
        #pragma unroll
        for (int a = 0; a < 3; a++) {
            float objmask = (mxi[a] > 0.7f) ? 0.0f : 1.0f;
            float omv;
            if (mk[a] >= 0) {
                float4 B0 = LAB[4 * mk[a] + 2];
                float4 B1 = LAB[4 * mk[a] + 3];
                float sc = B1.x, sc2 = sc * sc;
                lxy += (bce_t(X[a], B0.x) + bce_t(Y[a], B0.y)) * sc2;
                float dw = WR[a] - B0.z, dh = HR[a] - B0.w;
                lwh += 0.5f * sc2 * (dw * dw + dh * dh);
                float pco = fminf(fmaxf(OB[a], 1e-12f), 1.0f - 1e-7f);
                lobj += -__logf(pco);
                float dx = X[a] - B0.x, dy = Y[a] - B0.y, dob = OB[a] - 1.0f;
                l2 += dx * dx + dy * dy + sc2 * (dw * dw + dh * dh) + dob * dob;
                omv = OB[a];
                int ridx = atomicAdd((int*)(ws + WS_CNT_F), 1);
                float* R = ws + WS_REC_F + ridx * 8;
                R[0] = (float)b; R[1] = (float)a; R[2] = (float)p; R[3] = (float)mk[a];
                R[4] = X[a]; R[5] = Y[a]; R[6] = WR[a] * sc; R[7] = HR[a] * sc;
            } else {
                float oo = OB[a] * objmask;
                if (objmask != 0.0f) {
                    float pco = fminf(OB[a], 1.0f - 1e-7f);
                    lobj += -__logf(1.0f - pco);
                }
                l2 += oo * oo;
                omv = oo;
            }
            ws[WS_OMV_F + (size_t)(b * A_ + a) * HW + p] = omv;
        }
    }

    #pragma unroll
    for (int off = 32; off > 0; off >>= 1) {
        lxy += __shfl_down(lxy, off); lwh += __shfl_down(lwh, off);
        lobj += __shfl_down(lobj, off); l2 += __shfl_down(l2, off);
    }
    if (t < 128 && (t & 63) == 0) {
        redS[t >> 6][0] = lxy; redS[t >> 6][1] = lwh;
        redS[t >> 6][2] = lobj; redS[t >> 6][3] = l2;
    }
    __syncthreads();
    if (t == 0) {
        float* P = ws + WS_PART_F + (size_t)blk * 8;
        P[0] = redS[0][0] + redS[1][0];
        P[1] = redS[0][1] + redS[1][1];
        P[2] = redS[0][2] + redS[1][2];
        P[3] = 0.0f;
        P[4] = redS[0][3] + redS[1][3];
    }
}

// ---------------- writer: pure store-stream of dense out_m (zeros + obj ch from omv) ----------------
// slab float base = 6 + s*6460, base%4==2 -> head 2 floats, 1614 aligned float4, tail 2 floats
__global__ __launch_bounds__(256) void writer_kernel(const float* __restrict__ ws,
                                                     float* __restrict__ d_out) {
    const int t = threadIdx.x;
    const int s = blockIdx.x;                    // (b*3+a)*76 + j
    const int baj = s / F_, j = s - baj * F_;
    const float* om = ws + WS_OMV_F + (size_t)baj * HW + j * F_;
    float* slab = d_out + 6 + (size_t)s * SLAB;
    if (t == 0) { slab[0] = 0.0f; slab[1] = 0.0f; slab[6458] = 0.0f; slab[6459] = 0.0f; }
    float4* dst4 = (float4*)(slab + 2);
    for (int n = t; n < 1614; n += 256) {
        int f0 = 2 + 4 * n;
        int p = f0 / 85, r = f0 - 85 * p;
        float4 v = make_float4(0.0f, 0.0f, 0.0f, 0.0f);
        if (r >= 1 && r <= 4) ((float*)&v)[4 - r] = om[p];   // channel-4 slot
        dst4[n] = v;
    }
}

// ---------------- sparse: matched cells (<=800): f32 class dots + box-channel overwrite ----------------
__global__ __launch_bounds__(256) void sparse_kernel(const float* __restrict__ xin,
                                                     const float* __restrict__ conv_w,
                                                     float* __restrict__ ws,
                                                     float* __restrict__ d_out) {
    __shared__ float xcolS[256];
    __shared__ float rr[4][2];
    const int t = threadIdx.x;
    const int idx = blockIdx.x;
    float* P = ws + WS_PART_F + (size_t)(NCONV + idx) * 8;
    const int cnt = *(const int*)(ws + WS_CNT_F);
    if (idx >= cnt) { if (t < 8) P[t] = 0.0f; return; }
    const float* R = ws + WS_REC_F + idx * 8;
    const int b = (int)R[0], a = (int)R[1], p = (int)R[2], k = (int)R[3];
    const int j = p / F_, i = p - j * F_;
    xcolS[t] = xin[((size_t)b * CIN + t) * HW + p];
    __syncthreads();
    const float* Lr = ws + WS_LAB_F + (b * K_ + k) * 16;
    const int cl = (int)Lr[13];
    float* cell = d_out + 6 + (size_t)((b * A_ + a) * F_ + j) * SLAB + i * NCH;
    float lcls = 0.0f, l2 = 0.0f;
    if (t < 80) {
        const int o = a * NCH + 5 + t;
        const float4* wr4 = (const float4*)(conv_w + (size_t)o * CIN);
        float a0 = 0, a1 = 0, a2 = 0, a3 = 0;
        #pragma unroll 8
        for (int q = 0; q < 64; q++) {
            float4 wv = wr4[q];
            a0 = fmaf(wv.x, xcolS[q * 4 + 0], a0);
            a1 = fmaf(wv.y, xcolS[q * 4 + 1], a1);
            a2 = fmaf(wv.z, xcolS[q * 4 + 2], a2);
            a3 = fmaf(wv.w, xcolS[q * 4 + 3], a3);
        }
        float accv = ws[WS_BIAS_F + o] + ((a0 + a1) + (a2 + a3));
        float pc = sigm(accv);
        float tcv = (t == cl) ? 1.0f : 0.0f;
        lcls = bce_t(pc, tcv);
        float d = pc - tcv; l2 = d * d;
        cell[5 + t] = pc;
    } else if (t < 84) {
        cell[t - 80] = R[4 + (t - 80)];            // ch0=x, ch1=y, ch2=w*sc, ch3=h*sc (ch4 from writer)
    }
    #pragma unroll
    for (int off = 32; off > 0; off >>= 1) {
        lcls += __shfl_down(lcls, off); l2 += __shfl_down(l2, off);
    }
    if ((t & 63) == 0) { rr[t >> 6][0] = lcls; rr[t >> 6][1] = l2; }
    __syncthreads();
    if (t == 0) {
        P[0] = 0.0f; P[1] = 0.0f; P[2] = 0.0f;
        P[3] = rr[0][0] + rr[1][0] + rr[2][0] + rr[3][0];
        P[4] = rr[0][1] + rr[1][1] + rr[2][1] + rr[3][1];
    }
}

// ---------------- finish ----------------
__global__ void finish_kernel(const float* __restrict__ ws, float* __restrict__ d_out) {
    int t = threadIdx.x;
    const float* part = ws + WS_PART_F;
    float s0 = 0, s1 = 0, s2 = 0, s3 = 0, s4 = 0;
    for (int bidx = t; bidx < NROW; bidx += 256) {
        const float* P = part + (size_t)bidx * 8;
        s0 += P[0]; s1 += P[1]; s2 += P[2]; s3 += P[3]; s4 += P[4];
    }
    #pragma unroll
    for (int off = 32; off > 0; off >>= 1) {
        s0 += __shfl_down(s0, off); s1 += __shfl_down(s1, off);
        s2 += __shfl_down(s2, off); s3 += __shfl_down(s3, off);
        s4 += __shfl_down(s4, off);
    }
    __shared__ float red[4][5];
    if ((t & 63) == 0) {
        int w = t >> 6;
        red[w][0] = s0; red[w][1] = s1; red[w][2] = s2; red[w][3] = s3; red[w][4] = s4;
    }
    __syncthreads();
    if (t == 0) {
        float r0 = red[0][0] + red[1][0] + red[2][0] + red[3][0];
        float r1 = red[0][1] + red[1][1] + red[2][1] + red[3][1];
        float r2 = red[0][2] + red[1][2] + red[2][2] + red[3][2];
        float r3 = red[0][3] + red[1][3] + red[2][3] + red[3][3];
        float r4 = red[0][4] + red[1][4] + red[2][4] + red[3][4];
        d_out[0] = r0 + r1 + r2 + r3;
        d_out[1] = r0; d_out[2] = r1; d_out[3] = r2; d_out[4] = r3; d_out[5] = r4;
    }
}

extern "C" void kernel_launch(void* const* d_in, const int* in_sizes, int n_in,
                              void* d_out, int out_size, void* d_ws, size_t ws_size,
                              hipStream_t stream) {
    const float* xin    = (const float*)d_in[0];
    const float* labels = (const float*)d_in[1];
    const float* conv_w = (const float*)d_in[2];
    const float* conv_b = (const float*)d_in[3];
    float* out = (float*)d_out;
    float* ws  = (float*)d_ws;

    prep_kernel<<<3, 256, 0, stream>>>(conv_w, conv_b, labels, ws);
    convloss_kernel<<<NCONV, 256, 0, stream>>>(xin, ws);
    writer_kernel<<<B_ * A_ * F_, 256, 0, stream>>>(ws, out);
    sparse_kernel<<<NREC, 256, 0, stream>>>(xin, conv_w, ws, out);
    finish_kernel<<<1, 256, 0, stream>>>(ws, out);
}